// Round 1
// baseline (549.281 us; speedup 1.0000x reference)
//
#include <hip/hip_runtime.h>

typedef unsigned short ushort_t;
typedef __attribute__((ext_vector_type(8))) short short8;
typedef __attribute__((ext_vector_type(4))) float floatx4;

#define B_ 8
#define S_ 4096
#define E_ 1024
#define SD_ 8
#define M_TOTAL (B_ * S_)   /* 32768 rows */
#define NC 1032             /* E+SD real columns */
#define NPAD 1152           /* padded to multiple of 128 */

__device__ __forceinline__ ushort_t f2bf(float f) {
    union { float f; unsigned u; } v; v.f = f;
    unsigned u = v.u;
    unsigned r = (u + 0x7fffu + ((u >> 16) & 1u)) >> 16;  // RNE
    return (ushort_t)r;
}
__device__ __forceinline__ float bf2f(ushort_t h) {
    union { unsigned u; float f; } v; v.u = ((unsigned)h) << 16;
    return v.f;
}

// Async global->LDS, 16B per lane. LDS dest is wave-uniform base + lane*16.
__device__ __forceinline__ void stage16(ushort_t* lds_base_uniform, const ushort_t* g) {
#if __has_builtin(__builtin_amdgcn_global_load_lds)
    __builtin_amdgcn_global_load_lds(
        (const __attribute__((address_space(1))) void*)g,
        (__attribute__((address_space(3))) void*)lds_base_uniform, 16, 0, 0);
#else
    int lane = threadIdx.x & 63;
    *(short8*)((ushort_t*)lds_base_uniform + lane * 8) = *(const short8*)g;
#endif
}

// ---------------- prepass: fp32 -> bf16 conversions ----------------
__global__ void cvt_x4(const float* __restrict__ x, ushort_t* __restrict__ xb) {
    size_t i = ((size_t)blockIdx.x * 256 + threadIdx.x) * 4;
    float4 v = *(const float4*)(x + i);
    ushort4 o;
    o.x = f2bf(v.x); o.y = f2bf(v.y); o.z = f2bf(v.z); o.w = f2bf(v.w);
    *(ushort4*)(xb + i) = o;
}

// W_in [1024][1032] -> WinT [1152][1024] bf16 (transposed, zero-padded rows)
__global__ void prep_win(const float* __restrict__ W, ushort_t* __restrict__ WT) {
    int idx = blockIdx.x * 256 + threadIdx.x;  // over 1152*1024
    int n = idx >> 10, k = idx & 1023;
    WT[idx] = (n < NC) ? f2bf(W[(size_t)k * NC + n]) : (ushort_t)0;
}

// W_out [1032][1024] -> WoutT [1024][1152] bf16 (transposed, zero-padded cols)
__global__ void prep_wout(const float* __restrict__ W, ushort_t* __restrict__ WT) {
    int idx = blockIdx.x * 256 + threadIdx.x;  // over 1024*1152
    int n = idx / NPAD, k = idx - n * NPAD;
    WT[idx] = (k < NC) ? f2bf(W[(size_t)k * E_ + n]) : (ushort_t)0;
}

// ---------------- m97-style bf16 MFMA GEMM, B-transposed ----------------
// C[M][N] = A[M][K] * BT[N][K]^T + bias.  All of M,N multiples of 128; K mult of 32.
template <bool OUT_BF16>
__global__ __launch_bounds__(256, 2) void gemm_bt(
    const ushort_t* __restrict__ A, const ushort_t* __restrict__ BT,
    void* __restrict__ Cout, const float* __restrict__ bias,
    int K, int lda, int ldb, int ldc, int nbias)
{
    __shared__ __align__(16) ushort_t sA[128 * 32];
    __shared__ __align__(16) ushort_t sB[128 * 32];
    const int tid = threadIdx.x;
    const int wave = tid >> 6;
    const int lane = tid & 63;
    const int m0 = blockIdx.y * 128;
    const int n0 = blockIdx.x * 128;
    const int wm = wave >> 1, wn = wave & 1;   // 2x2 waves -> 64x64 each
    const int fr = lane & 15, fq = lane >> 4;  // fragment row / k-quad
    const int sr = lane >> 2;                  // staging row-in-16
    const int sc = (lane & 3) * 8;             // staging k-chunk (elems)

    floatx4 acc[4][4];
#pragma unroll
    for (int i = 0; i < 4; i++)
#pragma unroll
        for (int j = 0; j < 4; j++) acc[i][j] = (floatx4)0.f;

    const ushort_t* gA = A + (size_t)(m0 + wave * 32 + sr) * lda + sc;
    const ushort_t* gB = BT + (size_t)(n0 + wave * 32 + sr) * ldb + sc;

    for (int k0 = 0; k0 < K; k0 += 32) {
        __syncthreads();
        stage16(&sA[(wave * 32 + 0) * 32], gA + k0);
        stage16(&sA[(wave * 32 + 16) * 32], gA + (size_t)16 * lda + k0);
        stage16(&sB[(wave * 32 + 0) * 32], gB + k0);
        stage16(&sB[(wave * 32 + 16) * 32], gB + (size_t)16 * ldb + k0);
        __syncthreads();  // drains vmcnt(0) for global_load_lds

        short8 a[4], b[4];
#pragma unroll
        for (int i = 0; i < 4; i++)
            a[i] = *(const short8*)&sA[(wm * 64 + i * 16 + fr) * 32 + fq * 8];
#pragma unroll
        for (int j = 0; j < 4; j++)
            b[j] = *(const short8*)&sB[(wn * 64 + j * 16 + fr) * 32 + fq * 8];
#pragma unroll
        for (int i = 0; i < 4; i++)
#pragma unroll
            for (int j = 0; j < 4; j++)
                acc[i][j] = __builtin_amdgcn_mfma_f32_16x16x32_bf16(a[i], b[j], acc[i][j], 0, 0, 0);
    }

    // epilogue: C/D layout col=lane&15, row=(lane>>4)*4+reg   [m89-verified]
#pragma unroll
    for (int i = 0; i < 4; i++) {
        int row = m0 + wm * 64 + i * 16 + fq * 4;
#pragma unroll
        for (int j = 0; j < 4; j++) {
            int col = n0 + wn * 64 + j * 16 + fr;
            float bv = (col < nbias) ? bias[col] : 0.f;
#pragma unroll
            for (int r = 0; r < 4; r++) {
                float v = acc[i][j][r] + bv;
                if (OUT_BF16)
                    ((ushort_t*)Cout)[(size_t)(row + r) * ldc + col] = f2bf(v);
                else
                    ((float*)Cout)[(size_t)(row + r) * ldc + col] = v;
            }
        }
    }
}

// ---------------- gate = sigmoid(combined @ W_g + b_g) ----------------
// one wave per row; W_g^T staged in LDS padded to 1152 (stride-1 lane reads)
__global__ __launch_bounds__(256) void gate_kernel(
    const ushort_t* __restrict__ combined, const float* __restrict__ Wg,
    const float* __restrict__ bg, float* __restrict__ gate)
{
    __shared__ float WgT[8 * NPAD];  // 36864 B
    const int tid = threadIdx.x;
    for (int idx = tid; idx < 8 * NPAD; idx += 256) {
        int d = idx / NPAD, c = idx - d * NPAD;
        WgT[idx] = (c < NC) ? Wg[(size_t)c * 8 + d] : 0.f;
    }
    __syncthreads();
    const int wave = tid >> 6, lane = tid & 63;
    for (int rr = 0; rr < 8; rr++) {
        int m = blockIdx.x * 32 + wave * 8 + rr;
        const ushort_t* crow = combined + (size_t)m * NPAD;
        float acc[8] = {0.f, 0.f, 0.f, 0.f, 0.f, 0.f, 0.f, 0.f};
        for (int i = 0; i < 18; i++) {  // 18*64 = 1152, pad cols are zero
            float xv = bf2f(crow[i * 64 + lane]);
#pragma unroll
            for (int d = 0; d < 8; d++) acc[d] += xv * WgT[d * NPAD + i * 64 + lane];
        }
#pragma unroll
        for (int d = 0; d < 8; d++) {
#pragma unroll
            for (int off = 32; off >= 1; off >>= 1) acc[d] += __shfl_xor(acc[d], off);
        }
        if (lane == 0) {
#pragma unroll
            for (int d = 0; d < 8; d++) {
                float z = acc[d] + bg[d];
                gate[(size_t)m * 8 + d] = 1.f / (1.f + expf(-z));
            }
        }
    }
}

// ---------------- scan: state = g*state + (1-g)*si, chunked 2-pass ----------------
// chunk composition F(x)=A*x+Bv;  f_s(x)=g*x+(1-g)*si;  F' = f_s o F
__global__ void scan_chunks(const float* __restrict__ gate, const ushort_t* __restrict__ combined,
                            float* __restrict__ chA, float* __restrict__ chB)
{
    const int c = blockIdx.x, lane = threadIdx.x;
    const int b = lane >> 3, d = lane & 7;
    float A = 1.f, Bv = 0.f;
    const int s0 = c * 64;
    for (int s = s0; s < s0 + 64; s++) {
        size_t m = (size_t)b * S_ + s;
        float g = gate[m * 8 + d];
        float si = bf2f(combined[m * NPAD + E_ + d]);
        Bv = g * Bv + (1.f - g) * si;
        A *= g;
    }
    chA[c * 64 + lane] = A;
    chB[c * 64 + lane] = Bv;
}

__global__ void scan_apply(const float* __restrict__ gate, ushort_t* __restrict__ combined,
                           const float* __restrict__ chA, const float* __restrict__ chB,
                           float* __restrict__ final_state)
{
    const int c = blockIdx.x, lane = threadIdx.x;
    const int b = lane >> 3, d = lane & 7;
    float state = 0.f;  // state0 = 0
    for (int j = 0; j < c; j++)
        state = chA[j * 64 + lane] * state + chB[j * 64 + lane];
    const int s0 = c * 64;
    for (int s = s0; s < s0 + 64; s++) {
        size_t m = (size_t)b * S_ + s;
        float g = gate[m * 8 + d];
        float si = bf2f(combined[m * NPAD + E_ + d]);
        state = g * state + (1.f - g) * si;
        combined[m * NPAD + E_ + d] = f2bf(state);  // overwrite si with state (bf16) for GEMM3
    }
    if (c == 63) final_state[lane] = state;  // lane == b*8+d
}

extern "C" void kernel_launch(void* const* d_in, const int* in_sizes, int n_in,
                              void* d_out, int out_size, void* d_ws, size_t ws_size,
                              hipStream_t stream)
{
    (void)in_sizes; (void)n_in; (void)out_size; (void)ws_size;
    const float* x     = (const float*)d_in[0];
    const float* W_in  = (const float*)d_in[1];
    const float* b_in  = (const float*)d_in[2];
    const float* W_g   = (const float*)d_in[3];
    const float* b_g   = (const float*)d_in[4];
    const float* W_out = (const float*)d_in[5];
    const float* b_out = (const float*)d_in[6];

    // workspace layout (~81.3 MB total)
    ushort_t* combined = (ushort_t*)d_ws;                    // 32768*1152 bf16 = 75.5 MB
    ushort_t* WinT  = combined + (size_t)M_TOTAL * NPAD;     // 1152*1024 bf16
    ushort_t* WoutT = WinT + (size_t)NPAD * E_;              // 1024*1152 bf16
    float* gate = (float*)(WoutT + (size_t)E_ * NPAD);       // 32768*8 fp32
    float* chA  = gate + (size_t)M_TOTAL * SD_;              // 64*64
    float* chB  = chA + 64 * 64;                             // 64*64

    // x_bf16 lives in d_out's first 67 MB; dead before GEMM3 writes d_out.
    ushort_t* xb = (ushort_t*)d_out;
    float* outp = (float*)d_out;
    float* fs = outp + (size_t)M_TOTAL * E_;  // final_state at element 33554432

    cvt_x4<<<(M_TOTAL * E_) / 1024, 256, 0, stream>>>(x, xb);
    prep_win<<<(NPAD * E_) / 256, 256, 0, stream>>>(W_in, WinT);
    prep_wout<<<(E_ * NPAD) / 256, 256, 0, stream>>>(W_out, WoutT);

    // GEMM1: combined[32768][1152] = xb[32768][1024] @ WinT^T + b_in (bf16 out)
    gemm_bt<true><<<dim3(NPAD / 128, M_TOTAL / 128), 256, 0, stream>>>(
        xb, WinT, combined, b_in, E_, E_, E_, NPAD, NC);

    gate_kernel<<<M_TOTAL / 32, 256, 0, stream>>>(combined, W_g, b_g, gate);
    scan_chunks<<<64, 64, 0, stream>>>(gate, combined, chA, chB);
    scan_apply<<<64, 64, 0, stream>>>(gate, combined, chA, chB, fs);

    // GEMM3: out[32768][1024] = combined[32768][1152] @ WoutT^T + b_out (fp32 out)
    gemm_bt<false><<<dim3(E_ / 128, M_TOTAL / 128), 256, 0, stream>>>(
        combined, WoutT, outp, b_out, NPAD, NPAD, NPAD, E_, E_);
}

// Round 3
// 499.059 us; speedup vs baseline: 1.1006x; 1.1006x over previous
//
#include <hip/hip_runtime.h>

typedef unsigned short ushort_t;
typedef __attribute__((ext_vector_type(8))) short short8;
typedef __attribute__((ext_vector_type(4))) float floatx4;

#define B_ 8
#define S_ 4096
#define E_ 1024
#define SD_ 8
#define M_TOTAL (B_ * S_)   /* 32768 rows */
#define NC 1032             /* E+SD real columns */
#define NG 1040             /* E+SD+SD: real cols + fused gate-preact cols */
#define NPAD 1152           /* padded to multiple of 128 */

__device__ __forceinline__ ushort_t f2bf(float f) {
    union { float f; unsigned u; } v; v.f = f;
    unsigned u = v.u;
    unsigned r = (u + 0x7fffu + ((u >> 16) & 1u)) >> 16;  // RNE
    return (ushort_t)r;
}
__device__ __forceinline__ float bf2f(ushort_t h) {
    union { unsigned u; float f; } v; v.u = ((unsigned)h) << 16;
    return v.f;
}

// Async global->LDS, 16B per lane. LDS dest is wave-uniform base + lane*16.
__device__ __forceinline__ void stage16(ushort_t* lds_base_uniform, const ushort_t* g) {
    __builtin_amdgcn_global_load_lds(
        (const __attribute__((address_space(1))) void*)g,
        (__attribute__((address_space(3))) void*)lds_base_uniform, 16, 0, 0);
}

// ---------------- prepass: fp32 -> bf16 conversions ----------------
__global__ void cvt_x4(const float* __restrict__ x, ushort_t* __restrict__ xb) {
    size_t i = ((size_t)blockIdx.x * 256 + threadIdx.x) * 4;
    float4 v = *(const float4*)(x + i);
    ushort4 o;
    o.x = f2bf(v.x); o.y = f2bf(v.y); o.z = f2bf(v.z); o.w = f2bf(v.w);
    *(ushort4*)(xb + i) = o;
}

// W_comb[1024][8] = W_in[1024][1032] @ W_g[1032][8]  (fp32, one wave per row)
__global__ void wcomb_kernel(const float* __restrict__ W_in, const float* __restrict__ Wg,
                             float* __restrict__ Wc) {
    const int k = blockIdx.x;          // row 0..1023
    const int lane = threadIdx.x;      // 64
    float acc[8] = {0.f,0.f,0.f,0.f,0.f,0.f,0.f,0.f};
    for (int c = lane; c < NC; c += 64) {
        float w = W_in[(size_t)k * NC + c];
#pragma unroll
        for (int d = 0; d < 8; d++) acc[d] += w * Wg[(size_t)c * 8 + d];
    }
#pragma unroll
    for (int d = 0; d < 8; d++) {
#pragma unroll
        for (int off = 32; off >= 1; off >>= 1) acc[d] += __shfl_xor(acc[d], off);
    }
    if (lane == 0) {
#pragma unroll
        for (int d = 0; d < 8; d++) Wc[k * 8 + d] = acc[d];
    }
}

// biasExt[1152] = [b_in(1032) | b_in@W_g + b_g (8) | zeros(112)]
__global__ void bias_ext_kernel(const float* __restrict__ b_in, const float* __restrict__ Wg,
                                const float* __restrict__ bg, float* __restrict__ be) {
    int c = blockIdx.x * 256 + threadIdx.x;
    if (c >= NPAD) return;
    if (c < NC) { be[c] = b_in[c]; return; }
    if (c < NG) {
        int d = c - NC;
        float s = bg[d];
        for (int j = 0; j < NC; j++) s += b_in[j] * Wg[(size_t)j * 8 + d];
        be[c] = s;
        return;
    }
    be[c] = 0.f;
}

// W_in [1024][1032] (+ Wc gate cols) -> WinT [1152][1024] bf16
__global__ void prep_win(const float* __restrict__ W, const float* __restrict__ Wc,
                         ushort_t* __restrict__ WT) {
    int idx = blockIdx.x * 256 + threadIdx.x;  // over 1152*1024
    int n = idx >> 10, k = idx & 1023;
    float v;
    if (n < NC)       v = W[(size_t)k * NC + n];
    else if (n < NG)  v = Wc[k * 8 + (n - NC)];
    else              v = 0.f;
    WT[idx] = f2bf(v);
}

// W_out [1032][1024] -> WoutT [1024][1152] bf16 (transposed, zero-padded cols)
__global__ void prep_wout(const float* __restrict__ W, ushort_t* __restrict__ WT) {
    int idx = blockIdx.x * 256 + threadIdx.x;  // over 1024*1152
    int n = idx / NPAD, k = idx - n * NPAD;
    WT[idx] = (k < NC) ? f2bf(W[(size_t)k * E_ + n]) : (ushort_t)0;
}

// ---------------- m97-style bf16 MFMA GEMM, B-transposed ----------------
// C[M][N] = A[M][K] * BT[N][K]^T + bias.  M,N mult of 128; K mult of 32; gridDim.y mult of 8.
// XCD swizzle: within a band of 8 A-panels, flat%8 picks the panel, so each XCD's
// L2 sees one A-panel per band across all column tiles.
template <bool OUT_BF16>
__global__ __launch_bounds__(256, 2) void gemm_bt(
    const ushort_t* __restrict__ A, const ushort_t* __restrict__ BT,
    void* __restrict__ Cout, const float* __restrict__ bias,
    int K, int lda, int ldb, int ldc)
{
    __shared__ __align__(16) ushort_t sA[128 * 32];
    __shared__ __align__(16) ushort_t sB[128 * 32];
    const int tid = threadIdx.x;
    const int wave = tid >> 6;
    const int lane = tid & 63;

    const int gx = gridDim.x;
    int flat = blockIdx.y * gx + blockIdx.x;     // HW dispatch order (x fastest)
    const int band_size = 8 * gx;                // 8 panels per band
    int band = flat / band_size;
    int r = flat - band * band_size;
    const int m0 = (band * 8 + (r & 7)) * 128;   // panel: constant per-XCD within a band
    const int n0 = (r >> 3) * 128;

    const int wm = wave >> 1, wn = wave & 1;   // 2x2 waves -> 64x64 each
    const int fr = lane & 15, fq = lane >> 4;  // fragment row / k-quad
    const int sr = lane >> 2;                  // staging row-in-16
    const int sc = (lane & 3) * 8;             // staging k-chunk (elems)

    floatx4 acc[4][4];
#pragma unroll
    for (int i = 0; i < 4; i++)
#pragma unroll
        for (int j = 0; j < 4; j++) acc[i][j] = (floatx4)0.f;

    const ushort_t* gA = A + (size_t)(m0 + wave * 32 + sr) * lda + sc;
    const ushort_t* gB = BT + (size_t)(n0 + wave * 32 + sr) * ldb + sc;

    for (int k0 = 0; k0 < K; k0 += 32) {
        __syncthreads();
        stage16(&sA[(wave * 32 + 0) * 32], gA + k0);
        stage16(&sA[(wave * 32 + 16) * 32], gA + (size_t)16 * lda + k0);
        stage16(&sB[(wave * 32 + 0) * 32], gB + k0);
        stage16(&sB[(wave * 32 + 16) * 32], gB + (size_t)16 * ldb + k0);
        __syncthreads();  // drains vmcnt(0) for global_load_lds

        short8 a[4], b[4];
#pragma unroll
        for (int i = 0; i < 4; i++)
            a[i] = *(const short8*)&sA[(wm * 64 + i * 16 + fr) * 32 + fq * 8];
#pragma unroll
        for (int j = 0; j < 4; j++)
            b[j] = *(const short8*)&sB[(wn * 64 + j * 16 + fr) * 32 + fq * 8];
#pragma unroll
        for (int i = 0; i < 4; i++)
#pragma unroll
            for (int j = 0; j < 4; j++)
                acc[i][j] = __builtin_amdgcn_mfma_f32_16x16x32_bf16(a[i], b[j], acc[i][j], 0, 0, 0);
    }

    // epilogue: C/D layout col=lane&15, row=(lane>>4)*4+reg   [m89-verified]
#pragma unroll
    for (int i = 0; i < 4; i++) {
        int row = m0 + wm * 64 + i * 16 + fq * 4;
#pragma unroll
        for (int j = 0; j < 4; j++) {
            int col = n0 + wn * 64 + j * 16 + fr;
            float bv = bias[col];
#pragma unroll
            for (int r2 = 0; r2 < 4; r2++) {
                float v = acc[i][j][r2] + bv;
                if (OUT_BF16)
                    ((ushort_t*)Cout)[(size_t)(row + r2) * ldc + col] = f2bf(v);
                else
                    ((float*)Cout)[(size_t)(row + r2) * ldc + col] = v;
            }
        }
    }
}

// ---------------- scan: state = g*state + (1-g)*si, chunked 2-pass ----------------
// gate preact lives in combined cols 1032..1039 (fused into GEMM1); sigmoid applied here.
__global__ void scan_chunks(const ushort_t* __restrict__ combined,
                            float* __restrict__ chA, float* __restrict__ chB)
{
    const int c = blockIdx.x, lane = threadIdx.x;
    const int b = lane >> 3, d = lane & 7;
    float A = 1.f, Bv = 0.f;
    const int s0 = c * 64;
    for (int s = s0; s < s0 + 64; s++) {
        size_t m = (size_t)b * S_ + s;
        float z = bf2f(combined[m * NPAD + NC + d]);
        float g = 1.f / (1.f + __expf(-z));
        float si = bf2f(combined[m * NPAD + E_ + d]);
        Bv = g * Bv + (1.f - g) * si;
        A *= g;
    }
    chA[c * 64 + lane] = A;
    chB[c * 64 + lane] = Bv;
}

__global__ void scan_apply(ushort_t* __restrict__ combined,
                           const float* __restrict__ chA, const float* __restrict__ chB,
                           float* __restrict__ final_state)
{
    const int c = blockIdx.x, lane = threadIdx.x;
    const int b = lane >> 3, d = lane & 7;
    float state = 0.f;  // state0 = 0
    for (int j = 0; j < c; j++)
        state = chA[j * 64 + lane] * state + chB[j * 64 + lane];
    const int s0 = c * 64;
    for (int s = s0; s < s0 + 64; s++) {
        size_t m = (size_t)b * S_ + s;
        float z = bf2f(combined[m * NPAD + NC + d]);
        float g = 1.f / (1.f + __expf(-z));
        float si = bf2f(combined[m * NPAD + E_ + d]);
        state = g * state + (1.f - g) * si;
        combined[m * NPAD + E_ + d] = f2bf(state);  // overwrite si with state for GEMM3
    }
    if (c == 63) final_state[lane] = state;  // lane == b*8+d
}

extern "C" void kernel_launch(void* const* d_in, const int* in_sizes, int n_in,
                              void* d_out, int out_size, void* d_ws, size_t ws_size,
                              hipStream_t stream)
{
    (void)in_sizes; (void)n_in; (void)out_size; (void)ws_size;
    const float* x     = (const float*)d_in[0];
    const float* W_in  = (const float*)d_in[1];
    const float* b_in  = (const float*)d_in[2];
    const float* W_g   = (const float*)d_in[3];
    const float* b_g   = (const float*)d_in[4];
    const float* W_out = (const float*)d_in[5];
    const float* b_out = (const float*)d_in[6];

    // workspace layout (~80.2 MB total)
    ushort_t* combined = (ushort_t*)d_ws;                    // 32768*1152 bf16 = 75.5 MB
    ushort_t* WinT  = combined + (size_t)M_TOTAL * NPAD;     // 1152*1024 bf16
    ushort_t* WoutT = WinT + (size_t)NPAD * E_;              // 1024*1152 bf16
    float* Wc   = (float*)(WoutT + (size_t)E_ * NPAD);       // 1024*8 fp32
    float* be   = Wc + 1024 * 8;                             // 1152 fp32
    float* chA  = be + NPAD;                                 // 64*64
    float* chB  = chA + 64 * 64;                             // 64*64

    // x_bf16 lives in d_out's first 67 MB; dead before GEMM3 writes d_out.
    ushort_t* xb = (ushort_t*)d_out;
    float* outp = (float*)d_out;
    float* fs = outp + (size_t)M_TOTAL * E_;  // final_state at element 33554432

    cvt_x4<<<(M_TOTAL * E_) / 1024, 256, 0, stream>>>(x, xb);
    wcomb_kernel<<<E_, 64, 0, stream>>>(W_in, W_g, Wc);
    bias_ext_kernel<<<(NPAD + 255) / 256, 256, 0, stream>>>(b_in, W_g, b_g, be);
    prep_win<<<(NPAD * E_) / 256, 256, 0, stream>>>(W_in, Wc, WinT);
    prep_wout<<<(E_ * NPAD) / 256, 256, 0, stream>>>(W_out, WoutT);

    // GEMM1: combined[32768][1152] = xb[32768][1024] @ WinT^T + biasExt (bf16 out)
    // cols 0..1023 embed, 1024..1031 state_in, 1032..1039 gate preact, rest pad
    gemm_bt<true><<<dim3(NPAD / 128, M_TOTAL / 128), 256, 0, stream>>>(
        xb, WinT, combined, be, E_, E_, E_, NPAD);

    scan_chunks<<<64, 64, 0, stream>>>(combined, chA, chB);
    scan_apply<<<64, 64, 0, stream>>>(combined, chA, chB, fs);

    // GEMM3: out[32768][1024] = combined[32768][1152] @ WoutT^T + b_out (fp32 out)
    gemm_bt<false><<<dim3(E_ / 128, M_TOTAL / 128), 256, 0, stream>>>(
        combined, WoutT, outp, b_out, NPAD, NPAD, NPAD, E_);
}